// Round 4
// baseline (280.993 us; speedup 1.0000x reference)
//
#include <hip/hip_runtime.h>
#include <hip/hip_bf16.h>

#define B_ 4
#define C_ 512
#define L_ 2048
#define H_ 8
#define D_ 64
#define EPS_ 1e-5f

using short8 = __attribute__((ext_vector_type(8))) short;
using s4v    = __attribute__((ext_vector_type(4))) short;
using f32x4  = __attribute__((ext_vector_type(4))) float;

#if defined(__has_builtin)
#if __has_builtin(__builtin_amdgcn_exp2f)
#define EXP2(x) __builtin_amdgcn_exp2f(x)
#else
#define EXP2(x) exp2f(x)
#endif
#else
#define EXP2(x) exp2f(x)
#endif

// async global->LDS: each lane deposits 16B at (wave-uniform base + lane*16)
#define GLOAD_LDS16(g, l)                                                     \
  __builtin_amdgcn_global_load_lds(                                           \
      (const __attribute__((address_space(1))) void*)(g),                     \
      (__attribute__((address_space(3))) void*)(l), 16, 0, 0)

static __device__ __forceinline__ short f2bf(float f) {
  __hip_bfloat16 h = __float2bfloat16(f);
  return __builtin_bit_cast(short, h);
}
static __device__ __forceinline__ float bf2f(short s) {
  return __bfloat162float(__builtin_bit_cast(__hip_bfloat16, s));
}

// ---------------- Kernel 1: convert weights fp32 [in][out] -> bf16 [out][in] ----
__global__ __launch_bounds__(256) void k_convert_w(
    const float* __restrict__ Wq, const float* __restrict__ Wk,
    const float* __restrict__ Wv, const float* __restrict__ Wo,
    short* __restrict__ Wt) {
  int m = blockIdx.x, k0 = blockIdx.y * 32, n0 = blockIdx.z * 32;
  const float* W = (m == 0) ? Wq : (m == 1) ? Wk : (m == 2) ? Wv : Wo;
  __shared__ float T[32][33];
  int t = threadIdx.x;
  {
    int kl = t >> 3, n4 = (t & 7) * 4;
    float4 v = *(const float4*)(W + (size_t)(k0 + kl) * C_ + n0 + n4);
    T[kl][n4] = v.x; T[kl][n4 + 1] = v.y; T[kl][n4 + 2] = v.z; T[kl][n4 + 3] = v.w;
  }
  __syncthreads();
  {
    int nl = t >> 3, k4 = (t & 7) * 4;
    s4v o;
#pragma unroll
    for (int j = 0; j < 4; ++j) o[j] = f2bf(T[k4 + j][nl]);
    *(s4v*)(Wt + (size_t)(m * C_ + n0 + nl) * C_ + k0 + k4) = o;   // Wt[m][n][k]
  }
}

// ---------------- Kernel 2: transpose + pos + LayerNorm -> bf16 (B,L,C) --------
__global__ __launch_bounds__(256) void k_prep(
    const float* __restrict__ query, const float* __restrict__ kv,
    const float* __restrict__ pos,
    const float* __restrict__ qg, const float* __restrict__ qb,
    const float* __restrict__ kg, const float* __restrict__ kb,
    short* __restrict__ qn, short* __restrict__ kvn) {
  int l0 = blockIdx.x * 16;
  int b  = blockIdx.y;
  int z  = blockIdx.z;
  const float* src = z ? kv : query;
  const float* g   = z ? kg : qg;
  const float* be  = z ? kb : qb;
  short* dst       = z ? kvn : qn;

  __shared__ float T[16][516];
  __shared__ float mu_s[16], rs_s[16];
  int t = threadIdx.x;

  for (int i = 0; i < 32; ++i) {
    int flat = i * 256 + t;
    int c = flat >> 4, ll = flat & 15;
    T[ll][c] = src[(size_t)(b * C_ + c) * L_ + l0 + ll];
  }
  __syncthreads();
  for (int i = 0; i < 32; ++i) {
    int flat = i * 256 + t;
    int ll = flat >> 9, c = flat & 511;
    T[ll][c] += pos[(size_t)(l0 + ll) * C_ + c];
  }
  __syncthreads();
  {
    int row = t >> 4, j = t & 15;
    float s1 = 0.f, s2 = 0.f;
    for (int c = j; c < C_; c += 16) { float v = T[row][c]; s1 += v; s2 += v * v; }
    for (int m = 1; m < 16; m <<= 1) {
      s1 += __shfl_xor(s1, m, 64);
      s2 += __shfl_xor(s2, m, 64);
    }
    if (j == 0) {
      float mu  = s1 * (1.0f / C_);
      float var = s2 * (1.0f / C_) - mu * mu;
      mu_s[row] = mu;
      rs_s[row] = rsqrtf(var + EPS_);
    }
  }
  __syncthreads();
  for (int i = 0; i < 32; ++i) {
    int flat = i * 256 + t;
    int ll = flat >> 9, c = flat & 511;
    float v = (T[ll][c] - mu_s[ll]) * rs_s[ll] * g[c] + be[c];
    dst[(size_t)(b * L_ + l0 + ll) * C_ + c] = f2bf(v);
  }
}

// ---------------- Kernel 3: fused QKV projection GEMM (m97-style staging) ------
// Q output pre-scaled by 0.125*log2(e) so attention uses exp2 directly.
__global__ __launch_bounds__(256) void k_gemm_qkv(
    const short* __restrict__ qn, const short* __restrict__ kvn,
    const short* __restrict__ Wt,
    const float* __restrict__ bq, const float* __restrict__ bk, const float* __restrict__ bv,
    short* __restrict__ Qw, short* __restrict__ Kw, short* __restrict__ Vw) {
  int z = blockIdx.z;
  const short* X    = z ? kvn : qn;
  const short* W    = Wt + (size_t)z * C_ * C_;
  const float* bias = (z == 0) ? bq : (z == 1) ? bk : bv;
  short* Y          = (z == 0) ? Qw : (z == 1) ? Kw : Vw;
  float sc          = (z == 0) ? 0.18033688f : 1.0f;   // 1/8 * log2(e)

  int m0 = blockIdx.x * 128, n0 = blockIdx.y * 128;
  __shared__ alignas(16) short As[128 * 32];
  __shared__ alignas(16) short Bs[128 * 32];
  int t = threadIdx.x, lane = t & 63, w = t >> 6;
  int wm = w & 1, wn = w >> 1;
  int quad = lane >> 4, c = lane & 15;

  // staging: wave w covers rows [32w,32w+32); inst j covers 16 rows (1KB)
  const short* Ag = X + (size_t)(m0 + w * 32 + (lane >> 2)) * C_ + (lane & 3) * 8;
  const short* Bg = W + (size_t)(n0 + w * 32 + (lane >> 2)) * C_ + (lane & 3) * 8;

  f32x4 zero4 = {0.f, 0.f, 0.f, 0.f};
  f32x4 acc[4][4];
  for (int i = 0; i < 4; ++i) for (int j = 0; j < 4; ++j) acc[i][j] = zero4;

  for (int k0 = 0; k0 < C_; k0 += 32) {
    __syncthreads();
#pragma unroll
    for (int j = 0; j < 2; ++j) {
      GLOAD_LDS16(Ag + (size_t)j * 16 * C_ + k0, As + (w * 32 + j * 16) * 32);
      GLOAD_LDS16(Bg + (size_t)j * 16 * C_ + k0, Bs + (w * 32 + j * 16) * 32);
    }
    __syncthreads();
    short8 a[4], bf[4];
#pragma unroll
    for (int i = 0; i < 4; ++i)
      a[i]  = *(const short8*)(As + (wm * 64 + i * 16 + c) * 32 + quad * 8);
#pragma unroll
    for (int i = 0; i < 4; ++i)
      bf[i] = *(const short8*)(Bs + (wn * 64 + i * 16 + c) * 32 + quad * 8);
#pragma unroll
    for (int i = 0; i < 4; ++i)
#pragma unroll
      for (int j = 0; j < 4; ++j)
        acc[i][j] = __builtin_amdgcn_mfma_f32_16x16x32_bf16(a[i], bf[j], acc[i][j], 0, 0, 0);
  }

#pragma unroll
  for (int i = 0; i < 4; ++i)
#pragma unroll
    for (int j = 0; j < 4; ++j) {
      int colg = n0 + wn * 64 + j * 16 + c;
      float bia = bias[colg];
      s4v o;
#pragma unroll
      for (int r = 0; r < 4; ++r) o[r] = f2bf((acc[i][j][r] + bia) * sc);
      // rows are quad*4..quad*4+3 consecutive -> but layout is row-major strided C_;
      // store 4 scalar shorts (compiler folds addressing)
      int rowg = m0 + wm * 64 + i * 16 + quad * 4;
#pragma unroll
      for (int r = 0; r < 4; ++r) Y[(size_t)(rowg + r) * C_ + colg] = o[r];
    }
}

// ---------------- Kernel 3b: V -> V^T per head: Vtg[b][h][d][l] ----------------
__global__ __launch_bounds__(256) void k_transpose_v(
    const short* __restrict__ Vw, short* __restrict__ Vtg) {
  int l0 = blockIdx.x * 64, h = blockIdx.y, b = blockIdx.z;
  __shared__ alignas(16) short T[64 * 64];   // XOR-swizzled 16B chunks
  int t = threadIdx.x;
#pragma unroll
  for (int p = 0; p < 2; ++p) {
    int flat = p * 256 + t;
    int l = flat >> 3, cc = flat & 7;
    int sw = (l & 7) ^ ((l >> 3) & 7);
    *(short8*)(T + l * 64 + ((cc ^ sw) << 3)) =
        *(const short8*)(Vw + ((size_t)(b * L_ + l0 + l) * H_ + h) * D_ + (cc << 3));
  }
  __syncthreads();
#pragma unroll
  for (int p = 0; p < 2; ++p) {
    int flat = p * 256 + t;
    int d = flat >> 3, l8 = (flat & 7) * 8;
    int sw_hi = (l8 >> 3) & 7;
    short8 o;
#pragma unroll
    for (int j = 0; j < 8; ++j) {
      int pc = (d >> 3) ^ j ^ sw_hi;
      o[j] = T[(l8 + j) * 64 + (pc << 3) + (d & 7)];
    }
    *(short8*)(Vtg + ((size_t)(b * H_ + h) * D_ + d) * L_ + l0 + l8) = o;
  }
}

// ---------------- Kernel 4: attention -----------------------------------------
// Block = 64 q rows; wave (qh = w&1) owns 32 q rows, (ls = w>>1) owns lr half.
// S^T = K.Q^T (C-layout row=lr,col=q); P^T via per-(wave,strip) LDS buffer;
// O^T = V^T.P^T. Q pre-scaled by 0.125*log2(e); P = exp2(S), no clamp needed.
#define LDP 72
#define LDC 68
__global__ __launch_bounds__(256, 3) void k_attn(
    const short* __restrict__ Qw, const short* __restrict__ Kw,
    const short* __restrict__ Vtg, short* __restrict__ Ow) {
  int l0 = blockIdx.x * 64;
  int h  = blockIdx.y;
  int b  = blockIdx.z;
  __shared__ alignas(16) short Pw[4][2][16 * LDP];   // [wave][strip]
  __shared__ alignas(16) float Cbuf[64 * LDC];
  __shared__ float Lbuf[64];
  int t = threadIdx.x, lane = t & 63, w = t >> 6;
  int qh = w & 1, ls = w >> 1;
  int quad = lane >> 4, c = lane & 15;

  // Q B-fragments: 2 strips x 2 k-chunks (loaded once)
  short8 qa[2][2];
#pragma unroll
  for (int s = 0; s < 2; ++s) {
    const short* qp = Qw + ((size_t)(b * L_ + l0 + qh * 32 + s * 16 + c) * H_ + h) * D_ + quad * 8;
    qa[s][0] = *(const short8*)qp;
    qa[s][1] = *(const short8*)(qp + 32);
  }

  f32x4 zero4 = {0.f, 0.f, 0.f, 0.f};
  f32x4 acc[2][4];
#pragma unroll
  for (int s = 0; s < 2; ++s)
    for (int dt = 0; dt < 4; ++dt) acc[s][dt] = zero4;
  float lsum[2] = {0.f, 0.f};

  const short* Kb = Kw + ((size_t)(b * L_) * H_ + h) * D_;
  const short* Vb = Vtg + (size_t)(b * H_ + h) * D_ * L_;

  for (int lr0 = ls * 64; lr0 < L_; lr0 += 128) {
    short8 kf[4][2], vf[4][2];
#pragma unroll
    for (int T = 0; T < 4; ++T) {
      const short* kp = Kb + (size_t)(lr0 + T * 16 + c) * (H_ * D_) + quad * 8;
      kf[T][0] = *(const short8*)kp;
      kf[T][1] = *(const short8*)(kp + 32);
    }
#pragma unroll
    for (int dt = 0; dt < 4; ++dt) {
      const short* vp = Vb + (size_t)(dt * 16 + c) * L_ + lr0 + quad * 8;
      vf[dt][0] = *(const short8*)vp;
      vf[dt][1] = *(const short8*)(vp + 32);
    }

#pragma unroll
    for (int s = 0; s < 2; ++s) {
      f32x4 st[4] = {zero4, zero4, zero4, zero4};
#pragma unroll
      for (int T = 0; T < 4; ++T) {
        st[T] = __builtin_amdgcn_mfma_f32_16x16x32_bf16(kf[T][0], qa[s][0], st[T], 0, 0, 0);
        st[T] = __builtin_amdgcn_mfma_f32_16x16x32_bf16(kf[T][1], qa[s][1], st[T], 0, 0, 0);
      }
      short* pb = &Pw[w][s][0];
#pragma unroll
      for (int T = 0; T < 4; ++T) {
        s4v pk;
#pragma unroll
        for (int r = 0; r < 4; ++r) {
          float p = EXP2(st[T][r]);
          lsum[s] += p;
          pk[r] = f2bf(p);
        }
        *(s4v*)(pb + c * LDP + T * 16 + quad * 4) = pk;   // P^T[q][lr]
      }
#pragma unroll
      for (int hf = 0; hf < 2; ++hf) {
        short8 pf = *(const short8*)(pb + c * LDP + hf * 32 + quad * 8);
#pragma unroll
        for (int dt = 0; dt < 4; ++dt)
          acc[s][dt] = __builtin_amdgcn_mfma_f32_16x16x32_bf16(vf[dt][hf], pf, acc[s][dt], 0, 0, 0);
      }
    }
  }

  // per-q sums for this wave's lr half (all lanes end up with value for their c)
#pragma unroll
  for (int s = 0; s < 2; ++s) {
    lsum[s] += __shfl_xor(lsum[s], 16, 64);
    lsum[s] += __shfl_xor(lsum[s], 32, 64);
  }

  // cross-wave (lr halves) combine via LDS
  if (ls == 1) {
#pragma unroll
    for (int s = 0; s < 2; ++s) {
      int q = qh * 32 + s * 16 + c;
#pragma unroll
      for (int dt = 0; dt < 4; ++dt)
        *(f32x4*)(Cbuf + q * LDC + dt * 16 + quad * 4) = acc[s][dt];
      if (quad == 0) Lbuf[q] = lsum[s];
    }
  }
  __syncthreads();
  if (ls == 0) {
#pragma unroll
    for (int s = 0; s < 2; ++s) {
      int q = qh * 32 + s * 16 + c;
      float inv = 1.0f / (lsum[s] + Lbuf[q]);
#pragma unroll
      for (int dt = 0; dt < 4; ++dt) {
        f32x4 o = *(const f32x4*)(Cbuf + q * LDC + dt * 16 + quad * 4);
        s4v ov;
#pragma unroll
        for (int r = 0; r < 4; ++r) ov[r] = f2bf((acc[s][dt][r] + o[r]) * inv);
        *(s4v*)(Ow + ((size_t)(b * L_ + l0 + q) * H_ + h) * D_ + dt * 16 + quad * 4) = ov;
      }
    }
  }
}

// ---------------- Kernel 5: output projection + bias + residual + transpose ----
__global__ __launch_bounds__(256) void k_gemm_out(
    const short* __restrict__ Ow, const short* __restrict__ Wot,
    const float* __restrict__ bo, const short* __restrict__ qn,
    float* __restrict__ out) {
  int m0 = blockIdx.x * 128, n0 = blockIdx.y * 128;
  __shared__ alignas(16) short As[128 * 32];
  __shared__ alignas(16) short Bs[128 * 32];
  int t = threadIdx.x, lane = t & 63, w = t >> 6;
  int wm = w & 1, wn = w >> 1;
  int quad = lane >> 4, c = lane & 15;

  const short* Ag = Ow  + (size_t)(m0 + w * 32 + (lane >> 2)) * C_ + (lane & 3) * 8;
  const short* Bg = Wot + (size_t)(n0 + w * 32 + (lane >> 2)) * C_ + (lane & 3) * 8;

  f32x4 zero4 = {0.f, 0.f, 0.f, 0.f};
  f32x4 acc[4][4];
  for (int i = 0; i < 4; ++i) for (int j = 0; j < 4; ++j) acc[i][j] = zero4;

  for (int k0 = 0; k0 < C_; k0 += 32) {
    __syncthreads();
#pragma unroll
    for (int j = 0; j < 2; ++j) {
      GLOAD_LDS16(Ag + (size_t)j * 16 * C_ + k0, As + (w * 32 + j * 16) * 32);
      GLOAD_LDS16(Bg + (size_t)j * 16 * C_ + k0, Bs + (w * 32 + j * 16) * 32);
    }
    __syncthreads();
    short8 a[4], bf[4];
#pragma unroll
    for (int i = 0; i < 4; ++i)
      a[i]  = *(const short8*)(As + (wm * 64 + i * 16 + c) * 32 + quad * 8);
#pragma unroll
    for (int i = 0; i < 4; ++i)
      bf[i] = *(const short8*)(Bs + (wn * 64 + i * 16 + c) * 32 + quad * 8);
#pragma unroll
    for (int i = 0; i < 4; ++i)
#pragma unroll
      for (int j = 0; j < 4; ++j)
        acc[i][j] = __builtin_amdgcn_mfma_f32_16x16x32_bf16(a[i], bf[j], acc[i][j], 0, 0, 0);
  }

  int bb = m0 >> 11;                        // whole 128-row tile is inside one b
#pragma unroll
  for (int i = 0; i < 4; ++i)
#pragma unroll
    for (int j = 0; j < 4; ++j) {
      int colg = n0 + wn * 64 + j * 16 + c;
      float bia = bo[colg];
      int rowg = m0 + wm * 64 + i * 16 + quad * 4;
      int l = rowg & (L_ - 1);
      float4 vv;
      float* pv = &vv.x;
#pragma unroll
      for (int r = 0; r < 4; ++r)
        pv[r] = acc[i][j][r] + bia + bf2f(qn[(size_t)(rowg + r) * C_ + colg]);
      *(float4*)(out + ((size_t)bb * C_ + colg) * L_ + l) = vv;   // (B, C, L)
    }
}

extern "C" void kernel_launch(void* const* d_in, const int* in_sizes, int n_in,
                              void* d_out, int out_size, void* d_ws, size_t ws_size,
                              hipStream_t stream) {
  const float* query     = (const float*)d_in[0];
  const float* key_value = (const float*)d_in[1];
  const float* pos       = (const float*)d_in[2];
  const float* qg        = (const float*)d_in[3];
  const float* qb        = (const float*)d_in[4];
  const float* kg        = (const float*)d_in[5];
  const float* kb        = (const float*)d_in[6];
  const float* Wq        = (const float*)d_in[7];
  const float* bq        = (const float*)d_in[8];
  const float* Wk        = (const float*)d_in[9];
  const float* bk        = (const float*)d_in[10];
  const float* Wv        = (const float*)d_in[11];
  const float* bv        = (const float*)d_in[12];
  const float* Wo        = (const float*)d_in[13];
  const float* bo        = (const float*)d_in[14];
  float* out = (float*)d_out;

  char* ws = (char*)d_ws;
  const size_t SZ = (size_t)B_ * L_ * C_ * 2;   // 8 MB per bf16 (B,L,C) buffer
  short* qn  = (short*)(ws + 0 * SZ);
  short* kvn = (short*)(ws + 1 * SZ);
  short* Qw  = (short*)(ws + 2 * SZ);
  short* Kw  = (short*)(ws + 3 * SZ);
  short* Vw  = (short*)(ws + 4 * SZ);
  short* Ow  = (short*)(ws + 5 * SZ);
  short* Wt  = (short*)(ws + 6 * SZ);           // 4 x 512x512 bf16 = 2 MB
  short* Vtg = kvn;   // kvn dead after k_gemm_qkv; reuse for V^T [b][h][d][l]

  k_convert_w<<<dim3(4, 16, 16), 256, 0, stream>>>(Wq, Wk, Wv, Wo, Wt);
  k_prep<<<dim3(L_ / 16, B_, 2), 256, 0, stream>>>(query, key_value, pos, qg, qb, kg, kb, qn, kvn);
  k_gemm_qkv<<<dim3(8192 / 128, C_ / 128, 3), 256, 0, stream>>>(qn, kvn, Wt, bq, bk, bv, Qw, Kw, Vw);
  k_transpose_v<<<dim3(L_ / 64, H_, B_), 256, 0, stream>>>(Vw, Vtg);
  k_attn<<<dim3(L_ / 64, H_, B_), 256, 0, stream>>>(Qw, Kw, Vtg, Ow);
  k_gemm_out<<<dim3(8192 / 128, C_ / 128, 1), 256, 0, stream>>>(Ow, Wt + (size_t)3 * C_ * C_, bo, qn, out);
}

// Round 5
// 280.122 us; speedup vs baseline: 1.0031x; 1.0031x over previous
//
#include <hip/hip_runtime.h>
#include <hip/hip_bf16.h>

#define B_ 4
#define C_ 512
#define L_ 2048
#define H_ 8
#define D_ 64
#define EPS_ 1e-5f

using short8 = __attribute__((ext_vector_type(8))) short;
using s4v    = __attribute__((ext_vector_type(4))) short;
using f32x4  = __attribute__((ext_vector_type(4))) float;

#if defined(__has_builtin)
#if __has_builtin(__builtin_amdgcn_exp2f)
#define EXP2(x) __builtin_amdgcn_exp2f(x)
#else
#define EXP2(x) exp2f(x)
#endif
#else
#define EXP2(x) exp2f(x)
#endif

// async global->LDS: each lane deposits 16B at (wave-uniform base + lane*16)
#define GLOAD_LDS16(g, l)                                                     \
  __builtin_amdgcn_global_load_lds(                                           \
      (const __attribute__((address_space(1))) void*)(g),                     \
      (__attribute__((address_space(3))) void*)(l), 16, 0, 0)

static __device__ __forceinline__ short f2bf(float f) {
  __hip_bfloat16 h = __float2bfloat16(f);
  return __builtin_bit_cast(short, h);
}
static __device__ __forceinline__ float bf2f(short s) {
  return __bfloat162float(__builtin_bit_cast(__hip_bfloat16, s));
}

// ---------------- Kernel 1: convert weights fp32 [in][out] -> bf16 [out][in] ----
__global__ __launch_bounds__(256) void k_convert_w(
    const float* __restrict__ Wq, const float* __restrict__ Wk,
    const float* __restrict__ Wv, const float* __restrict__ Wo,
    short* __restrict__ Wt) {
  int m = blockIdx.x, k0 = blockIdx.y * 32, n0 = blockIdx.z * 32;
  const float* W = (m == 0) ? Wq : (m == 1) ? Wk : (m == 2) ? Wv : Wo;
  __shared__ float T[32][33];
  int t = threadIdx.x;
  {
    int kl = t >> 3, n4 = (t & 7) * 4;
    float4 v = *(const float4*)(W + (size_t)(k0 + kl) * C_ + n0 + n4);
    T[kl][n4] = v.x; T[kl][n4 + 1] = v.y; T[kl][n4 + 2] = v.z; T[kl][n4 + 3] = v.w;
  }
  __syncthreads();
  {
    int nl = t >> 3, k4 = (t & 7) * 4;
    s4v o;
#pragma unroll
    for (int j = 0; j < 4; ++j) o[j] = f2bf(T[k4 + j][nl]);
    *(s4v*)(Wt + (size_t)(m * C_ + n0 + nl) * C_ + k0 + k4) = o;   // Wt[m][n][k]
  }
}

// ---------------- Kernel 2: transpose + pos + LayerNorm -> bf16 (B,L,C) --------
__global__ __launch_bounds__(256) void k_prep(
    const float* __restrict__ query, const float* __restrict__ kv,
    const float* __restrict__ pos,
    const float* __restrict__ qg, const float* __restrict__ qb,
    const float* __restrict__ kg, const float* __restrict__ kb,
    short* __restrict__ qn, short* __restrict__ kvn) {
  int l0 = blockIdx.x * 16;
  int b  = blockIdx.y;
  int z  = blockIdx.z;
  const float* src = z ? kv : query;
  const float* g   = z ? kg : qg;
  const float* be  = z ? kb : qb;
  short* dst       = z ? kvn : qn;

  __shared__ alignas(16) float T[16][516];
  __shared__ float mu_s[16], rs_s[16];
  int t = threadIdx.x;

  // load src (B,C,L): float4 along l (16 c per wave, 64B contiguous per c)
#pragma unroll
  for (int i = 0; i < 8; ++i) {
    int idx = i * 256 + t;
    int cc = idx >> 2, lg = (idx & 3) * 4;
    float4 v = *(const float4*)(src + (size_t)(b * C_ + cc) * L_ + l0 + lg);
    T[lg + 0][cc] = v.x; T[lg + 1][cc] = v.y; T[lg + 2][cc] = v.z; T[lg + 3][cc] = v.w;
  }
  __syncthreads();
  // add pos: float4 over c (fully coalesced)
#pragma unroll
  for (int i = 0; i < 8; ++i) {
    int idx = i * 256 + t;
    int ll = idx >> 7, c4 = (idx & 127) * 4;
    float4 p = *(const float4*)(pos + (size_t)(l0 + ll) * C_ + c4);
    float4* tp = (float4*)&T[ll][c4];
    float4 cur = *tp;
    cur.x += p.x; cur.y += p.y; cur.z += p.z; cur.w += p.w;
    *tp = cur;
  }
  __syncthreads();
  // stats: 16 threads per row
  {
    int row = t >> 4, j = t & 15;
    float s1 = 0.f, s2 = 0.f;
    for (int c = j; c < C_; c += 16) { float v = T[row][c]; s1 += v; s2 += v * v; }
    for (int m = 1; m < 16; m <<= 1) {
      s1 += __shfl_xor(s1, m, 64);
      s2 += __shfl_xor(s2, m, 64);
    }
    if (j == 0) {
      float mu  = s1 * (1.0f / C_);
      float var = s2 * (1.0f / C_) - mu * mu;
      mu_s[row] = mu;
      rs_s[row] = rsqrtf(var + EPS_);
    }
  }
  __syncthreads();
  // normalize + write bf16 (B,L,C): s4v stores, coalesced
#pragma unroll
  for (int i = 0; i < 8; ++i) {
    int idx = i * 256 + t;
    int ll = idx >> 7, c4 = (idx & 127) * 4;
    float4 v  = *(const float4*)&T[ll][c4];
    float4 gv = *(const float4*)(g + c4);
    float4 bv = *(const float4*)(be + c4);
    float mu = mu_s[ll], rs = rs_s[ll];
    s4v o;
    o[0] = f2bf((v.x - mu) * rs * gv.x + bv.x);
    o[1] = f2bf((v.y - mu) * rs * gv.y + bv.y);
    o[2] = f2bf((v.z - mu) * rs * gv.z + bv.z);
    o[3] = f2bf((v.w - mu) * rs * gv.w + bv.w);
    *(s4v*)(dst + (size_t)(b * L_ + l0 + ll) * C_ + c4) = o;
  }
}

// ---------------- Kernel 3: fused QKV projection GEMM (m97-style staging) ------
// Q pre-scaled by 0.125*log2(e); V (z==2) stored directly transposed to
// Vtg[b][h][d][l] (fuses old k_transpose_v).
__global__ __launch_bounds__(256) void k_gemm_qkv(
    const short* __restrict__ qn, const short* __restrict__ kvn,
    const short* __restrict__ Wt,
    const float* __restrict__ bq, const float* __restrict__ bk, const float* __restrict__ bv,
    short* __restrict__ Qw, short* __restrict__ Kw, short* __restrict__ Vtg) {
  int z = blockIdx.z;
  const short* X    = z ? kvn : qn;
  const short* W    = Wt + (size_t)z * C_ * C_;
  const float* bias = (z == 0) ? bq : (z == 1) ? bk : bv;
  float sc          = (z == 0) ? 0.18033688f : 1.0f;   // 1/8 * log2(e)

  int m0 = blockIdx.x * 128, n0 = blockIdx.y * 128;
  __shared__ alignas(16) short As[128 * 32];
  __shared__ alignas(16) short Bs[128 * 32];
  int t = threadIdx.x, lane = t & 63, w = t >> 6;
  int wm = w & 1, wn = w >> 1;
  int quad = lane >> 4, c = lane & 15;

  const short* Ag = X + (size_t)(m0 + w * 32 + (lane >> 2)) * C_ + (lane & 3) * 8;
  const short* Bg = W + (size_t)(n0 + w * 32 + (lane >> 2)) * C_ + (lane & 3) * 8;

  f32x4 zero4 = {0.f, 0.f, 0.f, 0.f};
  f32x4 acc[4][4];
  for (int i = 0; i < 4; ++i) for (int j = 0; j < 4; ++j) acc[i][j] = zero4;

  for (int k0 = 0; k0 < C_; k0 += 32) {
    __syncthreads();
#pragma unroll
    for (int j = 0; j < 2; ++j) {
      GLOAD_LDS16(Ag + (size_t)j * 16 * C_ + k0, As + (w * 32 + j * 16) * 32);
      GLOAD_LDS16(Bg + (size_t)j * 16 * C_ + k0, Bs + (w * 32 + j * 16) * 32);
    }
    __syncthreads();
    short8 a[4], bf[4];
#pragma unroll
    for (int i = 0; i < 4; ++i)
      a[i]  = *(const short8*)(As + (wm * 64 + i * 16 + c) * 32 + quad * 8);
#pragma unroll
    for (int i = 0; i < 4; ++i)
      bf[i] = *(const short8*)(Bs + (wn * 64 + i * 16 + c) * 32 + quad * 8);
#pragma unroll
    for (int i = 0; i < 4; ++i)
#pragma unroll
      for (int j = 0; j < 4; ++j)
        acc[i][j] = __builtin_amdgcn_mfma_f32_16x16x32_bf16(a[i], bf[j], acc[i][j], 0, 0, 0);
  }

  if (z == 2) {
    // V: direct transposed store -> Vtg[b][h][d][l]; lanes give 32B segments
#pragma unroll
    for (int i = 0; i < 4; ++i)
#pragma unroll
      for (int j = 0; j < 4; ++j) {
        int colg = n0 + wn * 64 + j * 16 + c;
        float bia = bias[colg];
        int hh = colg >> 6, dd = colg & 63;
        int rowg = m0 + wm * 64 + i * 16 + quad * 4;
        int bb = rowg >> 11, l = rowg & (L_ - 1);
        s4v o;
#pragma unroll
        for (int r = 0; r < 4; ++r) o[r] = f2bf(acc[i][j][r] + bia);
        *(s4v*)(Vtg + ((size_t)(bb * H_ + hh) * D_ + dd) * L_ + l) = o;
      }
  } else {
    short* Y = (z == 0) ? Qw : Kw;
#pragma unroll
    for (int i = 0; i < 4; ++i)
#pragma unroll
      for (int j = 0; j < 4; ++j) {
        int colg = n0 + wn * 64 + j * 16 + c;
        float bia = bias[colg];
        int rowg = m0 + wm * 64 + i * 16 + quad * 4;
#pragma unroll
        for (int r = 0; r < 4; ++r)
          Y[(size_t)(rowg + r) * C_ + colg] = f2bf((acc[i][j][r] + bia) * sc);
      }
  }
}

// ---------------- Kernel 4: attention -----------------------------------------
// Block = 128 q rows. Wave: qh = w&1 owns 64 q (4 strips); ls = w>>1 owns lr half.
// Register double-buffered K prefetch; early V loads; S^T = K.Q^T; P^T via
// per-wave LDS; O^T = V^T.P^T. 1-D grid swizzle: all 16 tiles of one (b,h)
// share an XCD for L2 locality.
#define LDP 72
#define LDC 68
__global__ __launch_bounds__(256, 2) void k_attn(
    const short* __restrict__ Qw, const short* __restrict__ Kw,
    const short* __restrict__ Vtg, short* __restrict__ Ow) {
  int bh = blockIdx.x & 31;
  int l0 = (blockIdx.x >> 5) * 128;
  int b = bh >> 3, h = bh & 7;
  __shared__ alignas(16) short Pw[4][16 * LDP];
  __shared__ alignas(16) float Cbuf[128 * LDC];
  __shared__ float Lbuf[128];
  int t = threadIdx.x, lane = t & 63, w = t >> 6;
  int qh = w & 1, ls = w >> 1;
  int quad = lane >> 4, c = lane & 15;

  // Q B-fragments: 4 strips x 2 k-chunks (loaded once)
  short8 qa[4][2];
#pragma unroll
  for (int s = 0; s < 4; ++s) {
    const short* qp = Qw + ((size_t)(b * L_ + l0 + qh * 64 + s * 16 + c) * H_ + h) * D_ + quad * 8;
    qa[s][0] = *(const short8*)qp;
    qa[s][1] = *(const short8*)(qp + 32);
  }

  f32x4 zero4 = {0.f, 0.f, 0.f, 0.f};
  f32x4 acc[4][4];
#pragma unroll
  for (int s = 0; s < 4; ++s)
    for (int dt = 0; dt < 4; ++dt) acc[s][dt] = zero4;
  float lsum[4] = {0.f, 0.f, 0.f, 0.f};

  const short* Kb = Kw + ((size_t)(b * L_) * H_ + h) * D_;
  const short* Vb = Vtg + (size_t)(b * H_ + h) * D_ * L_;
  short* pb = &Pw[w][0];

  short8 kf[2][4][2];
  auto loadK = [&](int buf, int lr) {
#pragma unroll
    for (int T = 0; T < 4; ++T) {
      const short* kp = Kb + (size_t)(lr + T * 16 + c) * C_ + quad * 8;
      kf[buf][T][0] = *(const short8*)kp;
      kf[buf][T][1] = *(const short8*)(kp + 32);
    }
  };

  auto chunk = [&](int buf, int lr0, int lrn) {
    loadK(buf ^ 1, lrn);                       // prefetch next chunk's K
    short8 vf[4][2];                           // V early: hidden under QK+softmax
#pragma unroll
    for (int dt = 0; dt < 4; ++dt) {
      const short* vp = Vb + (size_t)(dt * 16 + c) * L_ + lr0 + quad * 8;
      vf[dt][0] = *(const short8*)vp;
      vf[dt][1] = *(const short8*)(vp + 32);
    }
#pragma unroll
    for (int s = 0; s < 4; ++s) {
      f32x4 st[4] = {zero4, zero4, zero4, zero4};
#pragma unroll
      for (int T = 0; T < 4; ++T) {
        st[T] = __builtin_amdgcn_mfma_f32_16x16x32_bf16(kf[buf][T][0], qa[s][0], st[T], 0, 0, 0);
        st[T] = __builtin_amdgcn_mfma_f32_16x16x32_bf16(kf[buf][T][1], qa[s][1], st[T], 0, 0, 0);
      }
#pragma unroll
      for (int T = 0; T < 4; ++T) {
        s4v pk;
#pragma unroll
        for (int r = 0; r < 4; ++r) {
          float p = EXP2(st[T][r]);
          lsum[s] += p;
          pk[r] = f2bf(p);
        }
        *(s4v*)(pb + c * LDP + T * 16 + quad * 4) = pk;   // P^T[q][lr]
      }
#pragma unroll
      for (int hf = 0; hf < 2; ++hf) {
        short8 pf = *(const short8*)(pb + c * LDP + hf * 32 + quad * 8);
#pragma unroll
        for (int dt = 0; dt < 4; ++dt)
          acc[s][dt] = __builtin_amdgcn_mfma_f32_16x16x32_bf16(vf[dt][hf], pf, acc[s][dt], 0, 0, 0);
      }
    }
  };

  loadK(0, ls * 64);
  for (int i = 0; i < 8; ++i) {
    int lr0 = ls * 64 + i * 256;
    chunk(0, lr0, lr0 + 128);
    chunk(1, lr0 + 128, (i == 7) ? ls * 64 : lr0 + 256);
  }

  // per-q sums for this wave's lr half
#pragma unroll
  for (int s = 0; s < 4; ++s) {
    lsum[s] += __shfl_xor(lsum[s], 16, 64);
    lsum[s] += __shfl_xor(lsum[s], 32, 64);
  }

  // cross-wave (lr halves) combine via LDS
  if (ls == 1) {
#pragma unroll
    for (int s = 0; s < 4; ++s) {
      int q = qh * 64 + s * 16 + c;
#pragma unroll
      for (int dt = 0; dt < 4; ++dt)
        *(f32x4*)(Cbuf + q * LDC + dt * 16 + quad * 4) = acc[s][dt];
      if (quad == 0) Lbuf[q] = lsum[s];
    }
  }
  __syncthreads();
  if (ls == 0) {
#pragma unroll
    for (int s = 0; s < 4; ++s) {
      int q = qh * 64 + s * 16 + c;
      float inv = 1.0f / (lsum[s] + Lbuf[q]);
#pragma unroll
      for (int dt = 0; dt < 4; ++dt) {
        f32x4 o = *(const f32x4*)(Cbuf + q * LDC + dt * 16 + quad * 4);
        s4v ov;
#pragma unroll
        for (int r = 0; r < 4; ++r) ov[r] = f2bf((acc[s][dt][r] + o[r]) * inv);
        *(s4v*)(Ow + ((size_t)(b * L_ + l0 + q) * H_ + h) * D_ + dt * 16 + quad * 4) = ov;
      }
    }
  }
}

// ---------------- Kernel 5: output projection + bias + residual + transpose ----
__global__ __launch_bounds__(256) void k_gemm_out(
    const short* __restrict__ Ow, const short* __restrict__ Wot,
    const float* __restrict__ bo, const short* __restrict__ qn,
    float* __restrict__ out) {
  int m0 = blockIdx.x * 128, n0 = blockIdx.y * 128;
  __shared__ alignas(16) short As[128 * 32];
  __shared__ alignas(16) short Bs[128 * 32];
  int t = threadIdx.x, lane = t & 63, w = t >> 6;
  int wm = w & 1, wn = w >> 1;
  int quad = lane >> 4, c = lane & 15;

  const short* Ag = Ow  + (size_t)(m0 + w * 32 + (lane >> 2)) * C_ + (lane & 3) * 8;
  const short* Bg = Wot + (size_t)(n0 + w * 32 + (lane >> 2)) * C_ + (lane & 3) * 8;

  f32x4 zero4 = {0.f, 0.f, 0.f, 0.f};
  f32x4 acc[4][4];
  for (int i = 0; i < 4; ++i) for (int j = 0; j < 4; ++j) acc[i][j] = zero4;

  for (int k0 = 0; k0 < C_; k0 += 32) {
    __syncthreads();
#pragma unroll
    for (int j = 0; j < 2; ++j) {
      GLOAD_LDS16(Ag + (size_t)j * 16 * C_ + k0, As + (w * 32 + j * 16) * 32);
      GLOAD_LDS16(Bg + (size_t)j * 16 * C_ + k0, Bs + (w * 32 + j * 16) * 32);
    }
    __syncthreads();
    short8 a[4], bf[4];
#pragma unroll
    for (int i = 0; i < 4; ++i)
      a[i]  = *(const short8*)(As + (wm * 64 + i * 16 + c) * 32 + quad * 8);
#pragma unroll
    for (int i = 0; i < 4; ++i)
      bf[i] = *(const short8*)(Bs + (wn * 64 + i * 16 + c) * 32 + quad * 8);
#pragma unroll
    for (int i = 0; i < 4; ++i)
#pragma unroll
      for (int j = 0; j < 4; ++j)
        acc[i][j] = __builtin_amdgcn_mfma_f32_16x16x32_bf16(a[i], bf[j], acc[i][j], 0, 0, 0);
  }

  int bb = m0 >> 11;
#pragma unroll
  for (int i = 0; i < 4; ++i)
#pragma unroll
    for (int j = 0; j < 4; ++j) {
      int colg = n0 + wn * 64 + j * 16 + c;
      float bia = bo[colg];
      int rowg = m0 + wm * 64 + i * 16 + quad * 4;
      int l = rowg & (L_ - 1);
      float4 vv;
      float* pv = &vv.x;
#pragma unroll
      for (int r = 0; r < 4; ++r)
        pv[r] = acc[i][j][r] + bia + bf2f(qn[(size_t)(rowg + r) * C_ + colg]);
      *(float4*)(out + ((size_t)bb * C_ + colg) * L_ + l) = vv;   // (B, C, L)
    }
}

extern "C" void kernel_launch(void* const* d_in, const int* in_sizes, int n_in,
                              void* d_out, int out_size, void* d_ws, size_t ws_size,
                              hipStream_t stream) {
  const float* query     = (const float*)d_in[0];
  const float* key_value = (const float*)d_in[1];
  const float* pos       = (const float*)d_in[2];
  const float* qg        = (const float*)d_in[3];
  const float* qb        = (const float*)d_in[4];
  const float* kg        = (const float*)d_in[5];
  const float* kb        = (const float*)d_in[6];
  const float* Wq        = (const float*)d_in[7];
  const float* bq        = (const float*)d_in[8];
  const float* Wk        = (const float*)d_in[9];
  const float* bk        = (const float*)d_in[10];
  const float* Wv        = (const float*)d_in[11];
  const float* bv        = (const float*)d_in[12];
  const float* Wo        = (const float*)d_in[13];
  const float* bo        = (const float*)d_in[14];
  float* out = (float*)d_out;

  char* ws = (char*)d_ws;
  const size_t SZ = (size_t)B_ * L_ * C_ * 2;   // 8 MB per bf16 buffer
  short* qn  = (short*)(ws + 0 * SZ);
  short* kvn = (short*)(ws + 1 * SZ);
  short* Qw  = (short*)(ws + 2 * SZ);
  short* Kw  = (short*)(ws + 3 * SZ);
  short* Vtg = (short*)(ws + 4 * SZ);           // [b][h][d][l]
  short* Ow  = (short*)(ws + 5 * SZ);
  short* Wt  = (short*)(ws + 6 * SZ);           // 4 x 512x512 bf16 = 2 MB

  k_convert_w<<<dim3(4, 16, 16), 256, 0, stream>>>(Wq, Wk, Wv, Wo, Wt);
  k_prep<<<dim3(L_ / 16, B_, 2), 256, 0, stream>>>(query, key_value, pos, qg, qb, kg, kb, qn, kvn);
  k_gemm_qkv<<<dim3(8192 / 128, C_ / 128, 3), 256, 0, stream>>>(qn, kvn, Wt, bq, bk, bv, Qw, Kw, Vtg);
  k_attn<<<dim3(512), 256, 0, stream>>>(Qw, Kw, Vtg, Ow);
  k_gemm_out<<<dim3(8192 / 128, C_ / 128, 1), 256, 0, stream>>>(Ow, Wt + (size_t)3 * C_ * C_, bo, qn, out);
}

// Round 6
// 235.479 us; speedup vs baseline: 1.1933x; 1.1896x over previous
//
#include <hip/hip_runtime.h>
#include <hip/hip_bf16.h>

#define B_ 4
#define C_ 512
#define L_ 2048
#define H_ 8
#define D_ 64
#define EPS_ 1e-5f

using short8 = __attribute__((ext_vector_type(8))) short;
using s4v    = __attribute__((ext_vector_type(4))) short;
using f32x4  = __attribute__((ext_vector_type(4))) float;

#if defined(__has_builtin)
#if __has_builtin(__builtin_amdgcn_exp2f)
#define EXP2(x) __builtin_amdgcn_exp2f(x)
#else
#define EXP2(x) exp2f(x)
#endif
#else
#define EXP2(x) exp2f(x)
#endif

// async global->LDS: each lane deposits 16B at (wave-uniform base + lane*16)
#define GLOAD_LDS16(g, l)                                                     \
  __builtin_amdgcn_global_load_lds(                                           \
      (const __attribute__((address_space(1))) void*)(g),                     \
      (__attribute__((address_space(3))) void*)(l), 16, 0, 0)

static __device__ __forceinline__ short f2bf(float f) {
  __hip_bfloat16 h = __float2bfloat16(f);
  return __builtin_bit_cast(short, h);
}
static __device__ __forceinline__ float bf2f(short s) {
  return __bfloat162float(__builtin_bit_cast(__hip_bfloat16, s));
}

// ---------------- Kernel 1: fused (weight convert+transpose) | (prep+LN) -------
// blocks [0,1024): Wt[m][n][k] = bf16(W[k][n]) via 32x32 LDS tile
// blocks [1024,3072): transpose + pos + LayerNorm -> bf16 (B,L,C)
__global__ __launch_bounds__(256) void k_pre(
    const float* __restrict__ Wq, const float* __restrict__ Wk,
    const float* __restrict__ Wv, const float* __restrict__ Wo,
    short* __restrict__ Wt,
    const float* __restrict__ query, const float* __restrict__ kv,
    const float* __restrict__ pos,
    const float* __restrict__ qg, const float* __restrict__ qb,
    const float* __restrict__ kg, const float* __restrict__ kb,
    short* __restrict__ qn, short* __restrict__ kvn) {
  __shared__ alignas(16) float SB[16 * 516 + 32];
  int t = threadIdx.x;
  int id = blockIdx.x;

  if (id < 1024) {
    // ---- weight convert ----
    int m = id >> 8, rest = id & 255;
    int k0 = (rest >> 4) * 32, n0 = (rest & 15) * 32;
    const float* W = (m == 0) ? Wq : (m == 1) ? Wk : (m == 2) ? Wv : Wo;
    float (*T)[33] = (float(*)[33])SB;
    {
      int kl = t >> 3, n4 = (t & 7) * 4;
      float4 v = *(const float4*)(W + (size_t)(k0 + kl) * C_ + n0 + n4);
      T[kl][n4] = v.x; T[kl][n4 + 1] = v.y; T[kl][n4 + 2] = v.z; T[kl][n4 + 3] = v.w;
    }
    __syncthreads();
    {
      int nl = t >> 3, k4 = (t & 7) * 4;
      s4v o;
#pragma unroll
      for (int j = 0; j < 4; ++j) o[j] = f2bf(T[k4 + j][nl]);
      *(s4v*)(Wt + (size_t)(m * C_ + n0 + nl) * C_ + k0 + k4) = o;
    }
    return;
  }

  // ---- prep + layernorm ----
  id -= 1024;
  int z  = id >> 9;
  int b  = (id >> 7) & 3;
  int l0 = (id & 127) * 16;
  const float* src = z ? kv : query;
  const float* g   = z ? kg : qg;
  const float* be  = z ? kb : qb;
  short* dst       = z ? kvn : qn;

  float (*T)[516] = (float(*)[516])SB;
  float* mu_s = SB + 16 * 516;
  float* rs_s = mu_s + 16;

#pragma unroll
  for (int i = 0; i < 8; ++i) {
    int idx = i * 256 + t;
    int cc = idx >> 2, lg = (idx & 3) * 4;
    float4 v = *(const float4*)(src + (size_t)(b * C_ + cc) * L_ + l0 + lg);
    T[lg + 0][cc] = v.x; T[lg + 1][cc] = v.y; T[lg + 2][cc] = v.z; T[lg + 3][cc] = v.w;
  }
  __syncthreads();
#pragma unroll
  for (int i = 0; i < 8; ++i) {
    int idx = i * 256 + t;
    int ll = idx >> 7, c4 = (idx & 127) * 4;
    float4 p = *(const float4*)(pos + (size_t)(l0 + ll) * C_ + c4);
    float4* tp = (float4*)&T[ll][c4];
    float4 cur = *tp;
    cur.x += p.x; cur.y += p.y; cur.z += p.z; cur.w += p.w;
    *tp = cur;
  }
  __syncthreads();
  {
    int row = t >> 4, j = t & 15;
    float s1 = 0.f, s2 = 0.f;
    for (int c = j; c < C_; c += 16) { float v = T[row][c]; s1 += v; s2 += v * v; }
    for (int m = 1; m < 16; m <<= 1) {
      s1 += __shfl_xor(s1, m, 64);
      s2 += __shfl_xor(s2, m, 64);
    }
    if (j == 0) {
      float mu  = s1 * (1.0f / C_);
      float var = s2 * (1.0f / C_) - mu * mu;
      mu_s[row] = mu;
      rs_s[row] = rsqrtf(var + EPS_);
    }
  }
  __syncthreads();
#pragma unroll
  for (int i = 0; i < 8; ++i) {
    int idx = i * 256 + t;
    int ll = idx >> 7, c4 = (idx & 127) * 4;
    float4 v  = *(const float4*)&T[ll][c4];
    float4 gv = *(const float4*)(g + c4);
    float4 bv = *(const float4*)(be + c4);
    float mu = mu_s[ll], rs = rs_s[ll];
    s4v o;
    o[0] = f2bf((v.x - mu) * rs * gv.x + bv.x);
    o[1] = f2bf((v.y - mu) * rs * gv.y + bv.y);
    o[2] = f2bf((v.z - mu) * rs * gv.z + bv.z);
    o[3] = f2bf((v.w - mu) * rs * gv.w + bv.w);
    *(s4v*)(dst + (size_t)(b * L_ + l0 + ll) * C_ + c4) = o;
  }
}

// ---------------- Kernel 2: fused QKV projection GEMM (BK=64, async staging) ---
// Q pre-scaled by 0.125*log2(e); V (z==2) stored directly transposed to
// Vtg[b][h][d][l].
__global__ __launch_bounds__(256) void k_gemm_qkv(
    const short* __restrict__ qn, const short* __restrict__ kvn,
    const short* __restrict__ Wt,
    const float* __restrict__ bq, const float* __restrict__ bk, const float* __restrict__ bv,
    short* __restrict__ Qw, short* __restrict__ Kw, short* __restrict__ Vtg) {
  int z = blockIdx.z;
  const short* X    = z ? kvn : qn;
  const short* W    = Wt + (size_t)z * C_ * C_;
  const float* bias = (z == 0) ? bq : (z == 1) ? bk : bv;
  float sc          = (z == 0) ? 0.18033688f : 1.0f;   // 1/8 * log2(e)

  int m0 = blockIdx.x * 128, n0 = blockIdx.y * 128;
  __shared__ alignas(16) short As[128 * 64];
  __shared__ alignas(16) short Bs[128 * 64];
  int t = threadIdx.x, lane = t & 63, w = t >> 6;
  int wm = w & 1, wn = w >> 1;
  int quad = lane >> 4, c = lane & 15;

  const short* Ag = X + (size_t)(m0 + w * 32 + (lane >> 3)) * C_ + (lane & 7) * 8;
  const short* Bg = W + (size_t)(n0 + w * 32 + (lane >> 3)) * C_ + (lane & 7) * 8;

  f32x4 zero4 = {0.f, 0.f, 0.f, 0.f};
  f32x4 acc[4][4];
  for (int i = 0; i < 4; ++i) for (int j = 0; j < 4; ++j) acc[i][j] = zero4;

  for (int k0 = 0; k0 < C_; k0 += 64) {
    __syncthreads();
#pragma unroll
    for (int j = 0; j < 4; ++j) {
      GLOAD_LDS16(Ag + (size_t)(j * 8) * C_ + k0, As + (w * 32 + j * 8) * 64);
      GLOAD_LDS16(Bg + (size_t)(j * 8) * C_ + k0, Bs + (w * 32 + j * 8) * 64);
    }
    __syncthreads();
#pragma unroll
    for (int kc = 0; kc < 2; ++kc) {
      short8 a[4], bf[4];
#pragma unroll
      for (int i = 0; i < 4; ++i)
        a[i]  = *(const short8*)(As + (wm * 64 + i * 16 + c) * 64 + kc * 32 + quad * 8);
#pragma unroll
      for (int j = 0; j < 4; ++j)
        bf[j] = *(const short8*)(Bs + (wn * 64 + j * 16 + c) * 64 + kc * 32 + quad * 8);
#pragma unroll
      for (int i = 0; i < 4; ++i)
#pragma unroll
        for (int j = 0; j < 4; ++j)
          acc[i][j] = __builtin_amdgcn_mfma_f32_16x16x32_bf16(a[i], bf[j], acc[i][j], 0, 0, 0);
    }
  }

  if (z == 2) {
    // V: direct transposed store -> Vtg[b][h][d][l]
#pragma unroll
    for (int i = 0; i < 4; ++i)
#pragma unroll
      for (int j = 0; j < 4; ++j) {
        int colg = n0 + wn * 64 + j * 16 + c;
        float bia = bias[colg];
        int hh = colg >> 6, dd = colg & 63;
        int rowg = m0 + wm * 64 + i * 16 + quad * 4;
        int bb = rowg >> 11, l = rowg & (L_ - 1);
        s4v o;
#pragma unroll
        for (int r = 0; r < 4; ++r) o[r] = f2bf(acc[i][j][r] + bia);
        *(s4v*)(Vtg + ((size_t)(bb * H_ + hh) * D_ + dd) * L_ + l) = o;
      }
  } else {
    short* Y = (z == 0) ? Qw : Kw;
#pragma unroll
    for (int i = 0; i < 4; ++i)
#pragma unroll
      for (int j = 0; j < 4; ++j) {
        int colg = n0 + wn * 64 + j * 16 + c;
        float bia = bias[colg];
        int rowg = m0 + wm * 64 + i * 16 + quad * 4;
#pragma unroll
        for (int r = 0; r < 4; ++r)
          Y[(size_t)(rowg + r) * C_ + colg] = f2bf((acc[i][j][r] + bia) * sc);
      }
  }
}

// ---------------- Kernel 3: attention (round-3 body + XCD-locality swizzle) ---
// Block = 128 q rows. Wave: qh = w&1 owns 64 q (4 strips); ls = w>>1 owns lr
// half. Direct-global K/V fragments (L2-resident via swizzle); S^T = K.Q^T;
// P^T via per-wave LDS; O^T = V^T.P^T. blockIdx % 32 == bh so all 16 q-tiles
// of one (b,h) land on the same XCD (round-robin dispatch), K+V = 2 MB/XCD L2.
#define LDP 72
#define LDC 68
__global__ __launch_bounds__(256, 2) void k_attn(
    const short* __restrict__ Qw, const short* __restrict__ Kw,
    const short* __restrict__ Vtg, short* __restrict__ Ow) {
  int bh = blockIdx.x & 31;
  int l0 = (blockIdx.x >> 5) * 128;
  int b = bh >> 3, h = bh & 7;
  __shared__ alignas(16) short Pw[4][16 * LDP];
  __shared__ alignas(16) float Cbuf[128 * LDC];
  __shared__ float Lbuf[128];
  int t = threadIdx.x, lane = t & 63, w = t >> 6;
  int qh = w & 1, ls = w >> 1;
  int quad = lane >> 4, c = lane & 15;

  // Q B-fragments: 4 strips x 2 k-chunks (loaded once)
  short8 qa[4][2];
#pragma unroll
  for (int s = 0; s < 4; ++s) {
    const short* qp = Qw + ((size_t)(b * L_ + l0 + qh * 64 + s * 16 + c) * H_ + h) * D_ + quad * 8;
    qa[s][0] = *(const short8*)qp;
    qa[s][1] = *(const short8*)(qp + 32);
  }

  f32x4 zero4 = {0.f, 0.f, 0.f, 0.f};
  f32x4 acc[4][4];
#pragma unroll
  for (int s = 0; s < 4; ++s)
    for (int dt = 0; dt < 4; ++dt) acc[s][dt] = zero4;
  float lsum[4] = {0.f, 0.f, 0.f, 0.f};

  const short* Kb = Kw + ((size_t)(b * L_) * H_ + h) * D_;
  const short* Vb = Vtg + (size_t)(b * H_ + h) * D_ * L_;
  short* pb = &Pw[w][0];

  for (int lr0 = ls * 64; lr0 < L_; lr0 += 128) {
    short8 kf[4][2], vf[4][2];
#pragma unroll
    for (int T = 0; T < 4; ++T) {
      const short* kp = Kb + (size_t)(lr0 + T * 16 + c) * C_ + quad * 8;
      kf[T][0] = *(const short8*)kp;
      kf[T][1] = *(const short8*)(kp + 32);
    }
#pragma unroll
    for (int dt = 0; dt < 4; ++dt) {
      const short* vp = Vb + (size_t)(dt * 16 + c) * L_ + lr0 + quad * 8;
      vf[dt][0] = *(const short8*)vp;
      vf[dt][1] = *(const short8*)(vp + 32);
    }

#pragma unroll
    for (int s = 0; s < 4; ++s) {
      f32x4 st[4] = {zero4, zero4, zero4, zero4};
#pragma unroll
      for (int T = 0; T < 4; ++T) {
        st[T] = __builtin_amdgcn_mfma_f32_16x16x32_bf16(kf[T][0], qa[s][0], st[T], 0, 0, 0);
        st[T] = __builtin_amdgcn_mfma_f32_16x16x32_bf16(kf[T][1], qa[s][1], st[T], 0, 0, 0);
      }
#pragma unroll
      for (int T = 0; T < 4; ++T) {
        s4v pk;
#pragma unroll
        for (int r = 0; r < 4; ++r) {
          float p = EXP2(st[T][r]);
          lsum[s] += p;
          pk[r] = f2bf(p);
        }
        *(s4v*)(pb + c * LDP + T * 16 + quad * 4) = pk;   // P^T[q][lr]
      }
#pragma unroll
      for (int hf = 0; hf < 2; ++hf) {
        short8 pf = *(const short8*)(pb + c * LDP + hf * 32 + quad * 8);
#pragma unroll
        for (int dt = 0; dt < 4; ++dt)
          acc[s][dt] = __builtin_amdgcn_mfma_f32_16x16x32_bf16(vf[dt][hf], pf, acc[s][dt], 0, 0, 0);
      }
    }
  }

  // per-q sums for this wave's lr half
#pragma unroll
  for (int s = 0; s < 4; ++s) {
    lsum[s] += __shfl_xor(lsum[s], 16, 64);
    lsum[s] += __shfl_xor(lsum[s], 32, 64);
  }

  // cross-wave (lr halves) combine via LDS
  if (ls == 1) {
#pragma unroll
    for (int s = 0; s < 4; ++s) {
      int q = qh * 64 + s * 16 + c;
#pragma unroll
      for (int dt = 0; dt < 4; ++dt)
        *(f32x4*)(Cbuf + q * LDC + dt * 16 + quad * 4) = acc[s][dt];
      if (quad == 0) Lbuf[q] = lsum[s];
    }
  }
  __syncthreads();
  if (ls == 0) {
#pragma unroll
    for (int s = 0; s < 4; ++s) {
      int q = qh * 64 + s * 16 + c;
      float inv = 1.0f / (lsum[s] + Lbuf[q]);
#pragma unroll
      for (int dt = 0; dt < 4; ++dt) {
        f32x4 o = *(const f32x4*)(Cbuf + q * LDC + dt * 16 + quad * 4);
        s4v ov;
#pragma unroll
        for (int r = 0; r < 4; ++r) ov[r] = f2bf((acc[s][dt][r] + o[r]) * inv);
        *(s4v*)(Ow + ((size_t)(b * L_ + l0 + q) * H_ + h) * D_ + dt * 16 + quad * 4) = ov;
      }
    }
  }
}

// ---------------- Kernel 4: output projection + bias + residual + transpose ----
__global__ __launch_bounds__(256) void k_gemm_out(
    const short* __restrict__ Ow, const short* __restrict__ Wot,
    const float* __restrict__ bo, const short* __restrict__ qn,
    float* __restrict__ out) {
  int m0 = blockIdx.x * 128, n0 = blockIdx.y * 128;
  __shared__ alignas(16) short As[128 * 64];
  __shared__ alignas(16) short Bs[128 * 64];
  int t = threadIdx.x, lane = t & 63, w = t >> 6;
  int wm = w & 1, wn = w >> 1;
  int quad = lane >> 4, c = lane & 15;

  const short* Ag = Ow  + (size_t)(m0 + w * 32 + (lane >> 3)) * C_ + (lane & 7) * 8;
  const short* Bg = Wot + (size_t)(n0 + w * 32 + (lane >> 3)) * C_ + (lane & 7) * 8;

  f32x4 zero4 = {0.f, 0.f, 0.f, 0.f};
  f32x4 acc[4][4];
  for (int i = 0; i < 4; ++i) for (int j = 0; j < 4; ++j) acc[i][j] = zero4;

  for (int k0 = 0; k0 < C_; k0 += 64) {
    __syncthreads();
#pragma unroll
    for (int j = 0; j < 4; ++j) {
      GLOAD_LDS16(Ag + (size_t)(j * 8) * C_ + k0, As + (w * 32 + j * 8) * 64);
      GLOAD_LDS16(Bg + (size_t)(j * 8) * C_ + k0, Bs + (w * 32 + j * 8) * 64);
    }
    __syncthreads();
#pragma unroll
    for (int kc = 0; kc < 2; ++kc) {
      short8 a[4], bf[4];
#pragma unroll
      for (int i = 0; i < 4; ++i)
        a[i]  = *(const short8*)(As + (wm * 64 + i * 16 + c) * 64 + kc * 32 + quad * 8);
#pragma unroll
      for (int j = 0; j < 4; ++j)
        bf[j] = *(const short8*)(Bs + (wn * 64 + j * 16 + c) * 64 + kc * 32 + quad * 8);
#pragma unroll
      for (int i = 0; i < 4; ++i)
#pragma unroll
        for (int j = 0; j < 4; ++j)
          acc[i][j] = __builtin_amdgcn_mfma_f32_16x16x32_bf16(a[i], bf[j], acc[i][j], 0, 0, 0);
    }
  }

  int bb = m0 >> 11;
#pragma unroll
  for (int i = 0; i < 4; ++i)
#pragma unroll
    for (int j = 0; j < 4; ++j) {
      int colg = n0 + wn * 64 + j * 16 + c;
      float bia = bo[colg];
      int rowg = m0 + wm * 64 + i * 16 + quad * 4;
      int l = rowg & (L_ - 1);
      float4 vv;
      float* pv = &vv.x;
#pragma unroll
      for (int r = 0; r < 4; ++r)
        pv[r] = acc[i][j][r] + bia + bf2f(qn[(size_t)(rowg + r) * C_ + colg]);
      *(float4*)(out + ((size_t)bb * C_ + colg) * L_ + l) = vv;   // (B, C, L)
    }
}

extern "C" void kernel_launch(void* const* d_in, const int* in_sizes, int n_in,
                              void* d_out, int out_size, void* d_ws, size_t ws_size,
                              hipStream_t stream) {
  const float* query     = (const float*)d_in[0];
  const float* key_value = (const float*)d_in[1];
  const float* pos       = (const float*)d_in[2];
  const float* qg        = (const float*)d_in[3];
  const float* qb        = (const float*)d_in[4];
  const float* kg        = (const float*)d_in[5];
  const float* kb        = (const float*)d_in[6];
  const float* Wq        = (const float*)d_in[7];
  const float* bq        = (const float*)d_in[8];
  const float* Wk        = (const float*)d_in[9];
  const float* bk        = (const float*)d_in[10];
  const float* Wv        = (const float*)d_in[11];
  const float* bv        = (const float*)d_in[12];
  const float* Wo        = (const float*)d_in[13];
  const float* bo        = (const float*)d_in[14];
  float* out = (float*)d_out;

  char* ws = (char*)d_ws;
  const size_t SZ = (size_t)B_ * L_ * C_ * 2;   // 8 MB per bf16 buffer
  short* qn  = (short*)(ws + 0 * SZ);
  short* kvn = (short*)(ws + 1 * SZ);
  short* Qw  = (short*)(ws + 2 * SZ);
  short* Kw  = (short*)(ws + 3 * SZ);
  short* Vtg = (short*)(ws + 4 * SZ);           // [b][h][d][l]
  short* Ow  = (short*)(ws + 5 * SZ);
  short* Wt  = (short*)(ws + 6 * SZ);           // 4 x 512x512 bf16 = 2 MB

  k_pre<<<dim3(3072), 256, 0, stream>>>(Wq, Wk, Wv, Wo, Wt,
                                        query, key_value, pos, qg, qb, kg, kb, qn, kvn);
  k_gemm_qkv<<<dim3(8192 / 128, C_ / 128, 3), 256, 0, stream>>>(qn, kvn, Wt, bq, bk, bv, Qw, Kw, Vtg);
  k_attn<<<dim3(512), 256, 0, stream>>>(Qw, Kw, Vtg, Ow);
  k_gemm_out<<<dim3(8192 / 128, C_ / 128, 1), 256, 0, stream>>>(Ow, Wt + (size_t)3 * C_ * C_, bo, qn, out);
}